// Round 12
// baseline (368.029 us; speedup 1.0000x reference)
//
#include <hip/hip_runtime.h>

#define N_NODES 75000
#define N_EDGES 1200000
#define DIM 64

#define EPB 2048                        // edges per hist/scatter block
#define NEB ((N_EDGES + EPB - 1) / EPB) // 586 edge-blocks
#define BKT_SHIFT 6
#define NPB 64                          // nodes per bucket (1<<6)
#define NBKT ((N_NODES + NPB - 1) / NPB) // 1172 buckets
#define NCTR (NBKT * NEB)               // 686,792 counters
#define NSB ((NCTR + 1023) / 1024)      // 671 scan blocks
#define NW_BLKS 2048                    // node_wave blocks inside fat
#define CSR_CAP 1536                    // max edges/bucket (mean 1024, +16 sigma)

typedef _Float16 half8 __attribute__((ext_vector_type(8)));  // 16B = 8 halfs

// Broadcast lane l (wave-uniform) of v to all lanes via v_readlane (VALU).
__device__ __forceinline__ float lane_bcf(float v, int l) {
    return __int_as_float(__builtin_amdgcn_readlane(__float_as_int(v), l));
}
__device__ __forceinline__ int lane_bci(int v, int l) {
    return __builtin_amdgcn_readlane(v, l);
}

// ===========================================================================
// Dispatch 1 — FAT: bucket-histogram (blocks 0..NEB-1) + node_wave (rest).
// R11 post-mortem: occupancy 30% at LB(256,4) — wave-starved, not
// VALU-bound. LB(256,8) legal (VGPR 52 <= 64) -> 32 waves/CU cap; NW_BLKS
// doubled to fill it. EPB halved to 2048 -> 586 hist blocks (2x parallel).
// ===========================================================================
__global__ __launch_bounds__(256, 8) void fat_kernel(
    const int* __restrict__ dst,
    const float* __restrict__ d_u, const float* __restrict__ p_u,
    const float* __restrict__ w_v, const float* __restrict__ w_q,
    const float* __restrict__ w_k,
    const float* __restrict__ e1, const float* __restrict__ e2,
    double* __restrict__ h_src, double* __restrict__ h_dst,
    _Float16* __restrict__ wvh,
    int* __restrict__ counters, unsigned int* __restrict__ pub) {

    if (blockIdx.x < NEB) {
        // ---- bucket histogram: 2048 edges -> 1172 LDS bins ----
        __shared__ int lbin[NBKT];
        for (int b = threadIdx.x; b < NBKT; b += 256) lbin[b] = 0;
        if (blockIdx.x == 0) {                 // zero 1024 >= NSB pub entries
            #pragma unroll
            for (int k = 0; k < 4; ++k) pub[threadIdx.x + 256 * k] = 0u;
        }
        __syncthreads();
        int base = blockIdx.x * EPB;
        #pragma unroll
        for (int k = 0; k < EPB / 256; ++k) {
            int e = base + k * 256 + threadIdx.x;
            if (e < N_EDGES) atomicAdd(&lbin[dst[e] >> BKT_SHIFT], 1);
        }
        __syncthreads();
        for (int b = threadIdx.x; b < NBKT; b += 256)
            counters[(size_t)b * NEB + blockIdx.x] = lbin[b];
        return;
    }

    // ---- node_wave: one wave per node, grid-strided (R8 body, f16 out) ----
    __shared__ double al_sh[DIM];
    __shared__ double bl_sh[DIM];
    int lane = threadIdx.x & 63;
    if (threadIdx.x < DIM) {
        double al = 0.0, bl = 0.0;
        #pragma unroll 8
        for (int j = 0; j < DIM; ++j) {
            al += (double)e1[j] * (double)w_k[j * DIM + threadIdx.x];
            bl += (double)e2[j] * (double)w_q[j * DIM + threadIdx.x];
        }
        al_sh[threadIdx.x] = al;
        bl_sh[threadIdx.x] = bl;
    }
    float w[DIM];
    const float4* wr = (const float4*)(w_v + (size_t)lane * DIM);
    #pragma unroll
    for (int k = 0; k < DIM / 4; ++k) {
        float4 v = wr[k];
        w[4 * k + 0] = v.x; w[4 * k + 1] = v.y;
        w[4 * k + 2] = v.z; w[4 * k + 3] = v.w;
    }
    __syncthreads();
    double al = al_sh[lane];
    double bl = bl_sh[lane];

    int wid = ((blockIdx.x - NEB) * 256 + threadIdx.x) >> 6;
    int nw = NW_BLKS * 4;
    for (int i = wid; i < N_NODES; i += nw) {
        float pl = p_u[(size_t)i * DIM + lane];
        float dl = d_u[(size_t)i * DIM + lane];
        double hs = (double)pl * al;
        #pragma unroll
        for (int off = 32; off > 0; off >>= 1) hs += __shfl_xor(hs, off, 64);
        double hd = (double)dl * bl;
        #pragma unroll
        for (int off = 32; off > 0; off >>= 1) hd += __shfl_xor(hd, off, 64);
        if (lane == 0) { h_src[i] = hs; h_dst[i] = hd; }
        float a0 = 0.f, a1 = 0.f, a2 = 0.f, a3 = 0.f;
        #pragma unroll
        for (int d = 0; d < DIM; d += 4) {
            a0 += w[d + 0] * lane_bcf(pl, d + 0);
            a1 += w[d + 1] * lane_bcf(pl, d + 1);
            a2 += w[d + 2] * lane_bcf(pl, d + 2);
            a3 += w[d + 3] * lane_bcf(pl, d + 3);
        }
        wvh[(size_t)i * DIM + lane] = (_Float16)((a0 + a1) + (a2 + a3));
    }
}

// ===========================================================================
// Dispatch 2 — exclusive scan of counters (bucket-major), in place.
// Backward-only lookback with persistent flags is deadlock-free even when
// block count (671) exceeds co-residency: later blocks only spin on flags
// already published by earlier (retired or resident) blocks.
// ===========================================================================
__global__ __launch_bounds__(1024) void scan_kernel(
    int* __restrict__ c, unsigned int* __restrict__ pub) {
    __shared__ int sh[1024];
    __shared__ int bpref;
    int tid = threadIdx.x;
    int i = blockIdx.x * 1024 + tid;
    int v = (i < NCTR) ? c[i] : 0;
    sh[tid] = v;
    __syncthreads();
    for (int off = 1; off < 1024; off <<= 1) {
        int t = (tid >= off) ? sh[tid - off] : 0;
        __syncthreads();
        sh[tid] += t;
        __syncthreads();
    }
    int incl = sh[tid];
    if (tid == 1023)
        atomicExch(&pub[blockIdx.x], (unsigned)incl | 0x80000000u);
    if (tid < 64) {
        int s = 0;
        for (int l = tid; l < (int)blockIdx.x; l += 64) {
            unsigned x;
            do { x = atomicAdd(&pub[l], 0u); } while (!(x & 0x80000000u));
            s += (int)(x & 0x7FFFFFFFu);
        }
        #pragma unroll
        for (int off = 32; off > 0; off >>= 1) s += __shfl_xor(s, off, 64);
        if (tid == 0) bpref = s;
    }
    __syncthreads();
    if (i < NCTR) c[i] = bpref + incl - v;        // exclusive prefix
}

// ===========================================================================
// Dispatch 3 — scatter edges into bucket-contiguous pairs[] via LDS ranks.
// pairs[pos] packs src (17 bits) | (dst&63)<<17. nt store (no write-alloc).
// 586 blocks (was 293) for 2x parallelism on the scattered-store phase.
// ===========================================================================
__global__ __launch_bounds__(256) void scatter_kernel(
    const int* __restrict__ src, const int* __restrict__ dst,
    const int* __restrict__ counters, int* __restrict__ pairs) {
    __shared__ int wk[NBKT];
    int eb = blockIdx.x;
    for (int b = threadIdx.x; b < NBKT; b += 256)
        wk[b] = counters[(size_t)b * NEB + eb];
    __syncthreads();
    int base = eb * EPB;
    #pragma unroll
    for (int k = 0; k < EPB / 256; ++k) {
        int e = base + k * 256 + threadIdx.x;
        if (e < N_EDGES) {
            int s = src[e];
            int d = dst[e];
            int pos = atomicAdd(&wk[d >> BKT_SHIFT], 1);     // LDS atomic
            __builtin_nontemporal_store(s | ((d & (NPB - 1)) << 17),
                                        &pairs[pos]);
        }
    }
}

// ===========================================================================
// Dispatch 4 — per-bucket counting sort IN LDS + fused gather.
// R11: occupancy 52% at 512-thr/LB(512,8). Reshape: 1024-thread blocks,
// LB(1024,2) -> 16 waves x 2 blocks = 32 waves/CU = 100% cap; demand
// 1172 x 16 = 18.7K waves >> 8.2K capacity -> saturated. 4 nodes/wave.
// ===========================================================================
__global__ __launch_bounds__(1024, 2) void sortgather_kernel(
    const int* __restrict__ counters, const int* __restrict__ pairs,
    const double* __restrict__ h_src, const double* __restrict__ h_dst,
    const _Float16* __restrict__ wvh, float* __restrict__ out) {
    __shared__ int csr[CSR_CAP];
    __shared__ int bin[NPB];
    __shared__ int pref[NPB];
    __shared__ int wk[NPB];
    int j = blockIdx.x;
    int tid = threadIdx.x;

    int start = counters[(size_t)j * NEB];
    int end = (j + 1 < NBKT) ? counters[(size_t)(j + 1) * NEB] : N_EDGES;
    int m = end - start;
    if (m > CSR_CAP) m = CSR_CAP;      // statistically impossible; mem-safety

    if (tid < NPB) bin[tid] = 0;
    __syncthreads();
    for (int k = tid; k < m; k += 1024)
        atomicAdd(&bin[(pairs[start + k] >> 17) & (NPB - 1)], 1);
    __syncthreads();
    // exclusive scan of the 64 bins
    if (tid < NPB) pref[tid] = bin[tid];
    __syncthreads();
    for (int off = 1; off < NPB; off <<= 1) {
        int t = 0;
        if (tid < NPB && tid >= off) t = pref[tid - off];
        __syncthreads();
        if (tid < NPB) pref[tid] += t;
        __syncthreads();
    }
    if (tid < NPB) { pref[tid] -= bin[tid]; wk[tid] = pref[tid]; }
    __syncthreads();
    for (int k = tid; k < m; k += 1024) {
        int p = pairs[start + k];
        int b = (p >> 17) & (NPB - 1);
        int r = atomicAdd(&wk[b], 1);
        csr[r] = p & 0x1FFFF;
    }
    __syncthreads();

    // ---- fused gather: wave w handles nodes w*4 .. w*4+3 ----
    int wvid = tid >> 6;               // 0..15
    int lane = tid & 63;
    for (int i = 0; i < 4; ++i) {
        int vloc = wvid * 4 + i;
        int vg = (j << BKT_SHIFT) + vloc;
        if (vg >= N_NODES) break;
        int deg = bin[vloc];
        int st = pref[vloc];
        double hd = h_dst[vg];

        if (deg <= 64) {
            int s0 = 0;
            double c0 = 0.0;
            if (lane < deg) {
                s0 = csr[st + lane];
                c0 = h_src[s0] + hd;
            }
            double r = c0;
            if (deg > 32) r += __shfl_xor(r, 32, 64);
            if (deg > 16) r += __shfl_xor(r, 16, 64);
            r += __shfl_xor(r, 8, 64);
            r += __shfl_xor(r, 4, 64);
            r += __shfl_xor(r, 2, 64);
            r += __shfl_xor(r, 1, 64);
            double inv = 1.0 / r;
            float cf0 = (lane < deg) ? (float)(c0 * inv) : 0.f;

            int g8 = lane >> 3;
            int sub8 = lane & 7;
            float ac[8];
            #pragma unroll
            for (int k = 0; k < 8; ++k) ac[k] = 0.f;
            int rounds = (deg + 7) >> 3;
            int jj = 0;
            for (; jj + 2 <= rounds; jj += 2) {
                int l0 = 8 * jj + g8;
                int l1 = l0 + 8;
                int   sA = __shfl(s0, l0, 64);
                float cA = __shfl(cf0, l0, 64);
                int   sB = __shfl(s0, l1, 64);
                float cB = __shfl(cf0, l1, 64);
                half8 vA = ((const half8*)(wvh + (size_t)sA * DIM))[sub8];
                half8 vB = ((const half8*)(wvh + (size_t)sB * DIM))[sub8];
                #pragma unroll
                for (int k = 0; k < 8; ++k) ac[k] += (float)vA[k] * cA;
                #pragma unroll
                for (int k = 0; k < 8; ++k) ac[k] += (float)vB[k] * cB;
            }
            if (jj < rounds) {
                int l0 = 8 * jj + g8;
                int   sA = __shfl(s0, l0, 64);
                float cA = __shfl(cf0, l0, 64);
                half8 vA = ((const half8*)(wvh + (size_t)sA * DIM))[sub8];
                #pragma unroll
                for (int k = 0; k < 8; ++k) ac[k] += (float)vA[k] * cA;
            }
            #pragma unroll
            for (int off = 8; off < 64; off <<= 1) {
                #pragma unroll
                for (int k = 0; k < 8; ++k) ac[k] += __shfl_xor(ac[k], off, 64);
            }
            if (g8 == 0) {
                float4* orow = (float4*)(out + (size_t)vg * DIM + sub8 * 8);
                float4 o0; o0.x = ac[0]; o0.y = ac[1]; o0.z = ac[2]; o0.w = ac[3];
                float4 o1; o1.x = ac[4]; o1.y = ac[5]; o1.z = ac[6]; o1.w = ac[7];
                orow[0] = o0; orow[1] = o1;
            }
        } else {
            double denom = 0.0;
            for (int base = 0; base < deg; base += 64) {
                int mm = deg - base; if (mm > 64) mm = 64;
                double c = 0.0;
                if (lane < mm) {
                    int s = csr[st + base + lane];
                    c = h_src[s] + hd;
                }
                #pragma unroll
                for (int off = 32; off > 0; off >>= 1) c += __shfl_xor(c, off, 64);
                denom += c;
            }
            double inv = 1.0 / denom;
            float acc = 0.f;
            for (int base = 0; base < deg; base += 64) {
                int mm = deg - base; if (mm > 64) mm = 64;
                int s1 = 0; float cf1 = 0.f;
                if (lane < mm) {
                    s1 = csr[st + base + lane];
                    cf1 = (float)((h_src[s1] + hd) * inv);
                }
                for (int q = 0; q < mm; ++q) {
                    int s = lane_bci(s1, q);
                    float cf = lane_bcf(cf1, q);
                    acc += (float)wvh[(size_t)s * DIM + lane] * cf;
                }
            }
            out[(size_t)vg * DIM + lane] = acc;
        }
    }
}

// ---------------------------------------------------------------------------
// Launch — 4 dispatches: fat, scan, scatter, sortgather. No memset.
// ---------------------------------------------------------------------------
extern "C" void kernel_launch(void* const* d_in, const int* in_sizes, int n_in,
                              void* d_out, int out_size, void* d_ws, size_t ws_size,
                              hipStream_t stream) {
    const float* d_u = (const float*)d_in[0];
    const float* p_u = (const float*)d_in[1];
    const float* w_q = (const float*)d_in[2];
    const float* w_k = (const float*)d_in[3];
    const float* w_v = (const float*)d_in[4];
    const float* e1  = (const float*)d_in[5];
    const float* e2  = (const float*)d_in[6];
    const int*   src = (const int*)d_in[7];
    const int*   dst = (const int*)d_in[8];
    float* out = (float*)d_out;

    // Workspace: doubles first (8B aligned), then halfs, then ints.
    double* h_src  = (double*)d_ws;
    double* h_dst  = h_src + N_NODES;
    _Float16* wvh  = (_Float16*)(h_dst + N_NODES);      // N_NODES*DIM halfs
    int* counters  = (int*)(wvh + (size_t)N_NODES * DIM); // NCTR ints
    unsigned int* pub = (unsigned int*)(counters + NCTR); // 1024
    int* pairs     = (int*)(pub + 1024);                  // N_EDGES ints

    fat_kernel<<<NEB + NW_BLKS, 256, 0, stream>>>(
        dst, d_u, p_u, w_v, w_q, w_k, e1, e2, h_src, h_dst, wvh,
        counters, pub);

    scan_kernel<<<NSB, 1024, 0, stream>>>(counters, pub);

    scatter_kernel<<<NEB, 256, 0, stream>>>(src, dst, counters, pairs);

    sortgather_kernel<<<NBKT, 1024, 0, stream>>>(
        counters, pairs, h_src, h_dst, wvh, out);
}

// Round 13
// 229.187 us; speedup vs baseline: 1.6058x; 1.6058x over previous
//
#include <hip/hip_runtime.h>

#define N_NODES 75000
#define N_EDGES 1200000
#define DIM 64

#define EPB 2048                        // edges per hist/scatter block
#define NEB ((N_EDGES + EPB - 1) / EPB) // 586 edge-blocks
#define BKT_SHIFT 6
#define NPB 64                          // nodes per bucket (1<<6)
#define NBKT ((N_NODES + NPB - 1) / NPB) // 1172 buckets
#define NCTR (NBKT * NEB)               // 686,792 counters
#define NSB ((NCTR + 1023) / 1024)      // 671 scan blocks
#define NW_BLKS 1024                    // node_wave blocks inside fat
#define CSR_CAP 1536                    // max edges/bucket (mean 1024, +16 sigma)

typedef _Float16 half8 __attribute__((ext_vector_type(8)));  // 16B = 8 halfs

// Broadcast lane l (wave-uniform) of v to all lanes via v_readlane (VALU).
__device__ __forceinline__ float lane_bcf(float v, int l) {
    return __int_as_float(__builtin_amdgcn_readlane(__float_as_int(v), l));
}
__device__ __forceinline__ int lane_bci(int v, int l) {
    return __builtin_amdgcn_readlane(v, l);
}

// ===========================================================================
// Dispatch 1 — FAT: bucket-histogram (blocks 0..NEB-1) + node_wave (rest).
// R12 post-mortem: LB(256,8) forced a 64-VGPR/thread budget < w[64]+state
// -> full scratch spill of w[] (VGPR 32, FETCH 430MB, 197us). REVERTED to
// the proven LB(256,4) / NW_BLKS=1024 config (52 VGPR, w[] in unified
// VGPR/AGPR file, 50.9us). fat's 30% occupancy is the register-capacity
// equilibrium for this body — do NOT raise the waves/EU bound again.
// ===========================================================================
__global__ __launch_bounds__(256, 4) void fat_kernel(
    const int* __restrict__ dst,
    const float* __restrict__ d_u, const float* __restrict__ p_u,
    const float* __restrict__ w_v, const float* __restrict__ w_q,
    const float* __restrict__ w_k,
    const float* __restrict__ e1, const float* __restrict__ e2,
    double* __restrict__ h_src, double* __restrict__ h_dst,
    _Float16* __restrict__ wvh,
    int* __restrict__ counters, unsigned int* __restrict__ pub) {

    if (blockIdx.x < NEB) {
        // ---- bucket histogram: 2048 edges -> 1172 LDS bins ----
        __shared__ int lbin[NBKT];
        for (int b = threadIdx.x; b < NBKT; b += 256) lbin[b] = 0;
        if (blockIdx.x == 0) {                 // zero 1024 >= NSB pub entries
            #pragma unroll
            for (int k = 0; k < 4; ++k) pub[threadIdx.x + 256 * k] = 0u;
        }
        __syncthreads();
        int base = blockIdx.x * EPB;
        #pragma unroll
        for (int k = 0; k < EPB / 256; ++k) {
            int e = base + k * 256 + threadIdx.x;
            if (e < N_EDGES) atomicAdd(&lbin[dst[e] >> BKT_SHIFT], 1);
        }
        __syncthreads();
        for (int b = threadIdx.x; b < NBKT; b += 256)
            counters[(size_t)b * NEB + blockIdx.x] = lbin[b];
        return;
    }

    // ---- node_wave: one wave per node, grid-strided (R8 body, f16 out) ----
    __shared__ double al_sh[DIM];
    __shared__ double bl_sh[DIM];
    int lane = threadIdx.x & 63;
    if (threadIdx.x < DIM) {
        double al = 0.0, bl = 0.0;
        #pragma unroll 8
        for (int j = 0; j < DIM; ++j) {
            al += (double)e1[j] * (double)w_k[j * DIM + threadIdx.x];
            bl += (double)e2[j] * (double)w_q[j * DIM + threadIdx.x];
        }
        al_sh[threadIdx.x] = al;
        bl_sh[threadIdx.x] = bl;
    }
    float w[DIM];
    const float4* wr = (const float4*)(w_v + (size_t)lane * DIM);
    #pragma unroll
    for (int k = 0; k < DIM / 4; ++k) {
        float4 v = wr[k];
        w[4 * k + 0] = v.x; w[4 * k + 1] = v.y;
        w[4 * k + 2] = v.z; w[4 * k + 3] = v.w;
    }
    __syncthreads();
    double al = al_sh[lane];
    double bl = bl_sh[lane];

    int wid = ((blockIdx.x - NEB) * 256 + threadIdx.x) >> 6;
    int nw = NW_BLKS * 4;
    for (int i = wid; i < N_NODES; i += nw) {
        float pl = p_u[(size_t)i * DIM + lane];
        float dl = d_u[(size_t)i * DIM + lane];
        double hs = (double)pl * al;
        #pragma unroll
        for (int off = 32; off > 0; off >>= 1) hs += __shfl_xor(hs, off, 64);
        double hd = (double)dl * bl;
        #pragma unroll
        for (int off = 32; off > 0; off >>= 1) hd += __shfl_xor(hd, off, 64);
        if (lane == 0) { h_src[i] = hs; h_dst[i] = hd; }
        float a0 = 0.f, a1 = 0.f, a2 = 0.f, a3 = 0.f;
        #pragma unroll
        for (int d = 0; d < DIM; d += 4) {
            a0 += w[d + 0] * lane_bcf(pl, d + 0);
            a1 += w[d + 1] * lane_bcf(pl, d + 1);
            a2 += w[d + 2] * lane_bcf(pl, d + 2);
            a3 += w[d + 3] * lane_bcf(pl, d + 3);
        }
        wvh[(size_t)i * DIM + lane] = (_Float16)((a0 + a1) + (a2 + a3));
    }
}

// ===========================================================================
// Dispatch 2 — exclusive scan of counters (bucket-major), in place.
// Backward-only lookback with persistent flags is deadlock-free even when
// block count (671) exceeds co-residency: later blocks only spin on flags
// already published by earlier (retired or resident) blocks.
// ===========================================================================
__global__ __launch_bounds__(1024) void scan_kernel(
    int* __restrict__ c, unsigned int* __restrict__ pub) {
    __shared__ int sh[1024];
    __shared__ int bpref;
    int tid = threadIdx.x;
    int i = blockIdx.x * 1024 + tid;
    int v = (i < NCTR) ? c[i] : 0;
    sh[tid] = v;
    __syncthreads();
    for (int off = 1; off < 1024; off <<= 1) {
        int t = (tid >= off) ? sh[tid - off] : 0;
        __syncthreads();
        sh[tid] += t;
        __syncthreads();
    }
    int incl = sh[tid];
    if (tid == 1023)
        atomicExch(&pub[blockIdx.x], (unsigned)incl | 0x80000000u);
    if (tid < 64) {
        int s = 0;
        for (int l = tid; l < (int)blockIdx.x; l += 64) {
            unsigned x;
            do { x = atomicAdd(&pub[l], 0u); } while (!(x & 0x80000000u));
            s += (int)(x & 0x7FFFFFFFu);
        }
        #pragma unroll
        for (int off = 32; off > 0; off >>= 1) s += __shfl_xor(s, off, 64);
        if (tid == 0) bpref = s;
    }
    __syncthreads();
    if (i < NCTR) c[i] = bpref + incl - v;        // exclusive prefix
}

// ===========================================================================
// Dispatch 3 — scatter edges into bucket-contiguous pairs[] via LDS ranks.
// pairs[pos] packs src (17 bits) | (dst&63)<<17. nt store (no write-alloc).
// ===========================================================================
__global__ __launch_bounds__(256) void scatter_kernel(
    const int* __restrict__ src, const int* __restrict__ dst,
    const int* __restrict__ counters, int* __restrict__ pairs) {
    __shared__ int wk[NBKT];
    int eb = blockIdx.x;
    for (int b = threadIdx.x; b < NBKT; b += 256)
        wk[b] = counters[(size_t)b * NEB + eb];
    __syncthreads();
    int base = eb * EPB;
    #pragma unroll
    for (int k = 0; k < EPB / 256; ++k) {
        int e = base + k * 256 + threadIdx.x;
        if (e < N_EDGES) {
            int s = src[e];
            int d = dst[e];
            int pos = atomicAdd(&wk[d >> BKT_SHIFT], 1);     // LDS atomic
            __builtin_nontemporal_store(s | ((d & (NPB - 1)) << 17),
                                        &pairs[pos]);
        }
    }
}

// ===========================================================================
// Dispatch 4 — per-bucket counting sort IN LDS + fused gather.
// 1024-thread blocks, LB(1024,2): 16 waves x 2 blocks = 32 waves/CU cap;
// demand 1172 x 16 = 18.7K waves. 4 nodes/wave. (R12: neutral vs 512-thr —
// occupancy lever exhausted; kept for the higher cap.)
// ===========================================================================
__global__ __launch_bounds__(1024, 2) void sortgather_kernel(
    const int* __restrict__ counters, const int* __restrict__ pairs,
    const double* __restrict__ h_src, const double* __restrict__ h_dst,
    const _Float16* __restrict__ wvh, float* __restrict__ out) {
    __shared__ int csr[CSR_CAP];
    __shared__ int bin[NPB];
    __shared__ int pref[NPB];
    __shared__ int wk[NPB];
    int j = blockIdx.x;
    int tid = threadIdx.x;

    int start = counters[(size_t)j * NEB];
    int end = (j + 1 < NBKT) ? counters[(size_t)(j + 1) * NEB] : N_EDGES;
    int m = end - start;
    if (m > CSR_CAP) m = CSR_CAP;      // statistically impossible; mem-safety

    if (tid < NPB) bin[tid] = 0;
    __syncthreads();
    for (int k = tid; k < m; k += 1024)
        atomicAdd(&bin[(pairs[start + k] >> 17) & (NPB - 1)], 1);
    __syncthreads();
    // exclusive scan of the 64 bins
    if (tid < NPB) pref[tid] = bin[tid];
    __syncthreads();
    for (int off = 1; off < NPB; off <<= 1) {
        int t = 0;
        if (tid < NPB && tid >= off) t = pref[tid - off];
        __syncthreads();
        if (tid < NPB) pref[tid] += t;
        __syncthreads();
    }
    if (tid < NPB) { pref[tid] -= bin[tid]; wk[tid] = pref[tid]; }
    __syncthreads();
    for (int k = tid; k < m; k += 1024) {
        int p = pairs[start + k];
        int b = (p >> 17) & (NPB - 1);
        int r = atomicAdd(&wk[b], 1);
        csr[r] = p & 0x1FFFF;
    }
    __syncthreads();

    // ---- fused gather: wave w handles nodes w*4 .. w*4+3 ----
    int wvid = tid >> 6;               // 0..15
    int lane = tid & 63;
    for (int i = 0; i < 4; ++i) {
        int vloc = wvid * 4 + i;
        int vg = (j << BKT_SHIFT) + vloc;
        if (vg >= N_NODES) break;
        int deg = bin[vloc];
        int st = pref[vloc];
        double hd = h_dst[vg];

        if (deg <= 64) {
            int s0 = 0;
            double c0 = 0.0;
            if (lane < deg) {
                s0 = csr[st + lane];
                c0 = h_src[s0] + hd;
            }
            double r = c0;
            if (deg > 32) r += __shfl_xor(r, 32, 64);
            if (deg > 16) r += __shfl_xor(r, 16, 64);
            r += __shfl_xor(r, 8, 64);
            r += __shfl_xor(r, 4, 64);
            r += __shfl_xor(r, 2, 64);
            r += __shfl_xor(r, 1, 64);
            double inv = 1.0 / r;
            float cf0 = (lane < deg) ? (float)(c0 * inv) : 0.f;

            int g8 = lane >> 3;
            int sub8 = lane & 7;
            float ac[8];
            #pragma unroll
            for (int k = 0; k < 8; ++k) ac[k] = 0.f;
            int rounds = (deg + 7) >> 3;
            int jj = 0;
            for (; jj + 2 <= rounds; jj += 2) {
                int l0 = 8 * jj + g8;
                int l1 = l0 + 8;
                int   sA = __shfl(s0, l0, 64);
                float cA = __shfl(cf0, l0, 64);
                int   sB = __shfl(s0, l1, 64);
                float cB = __shfl(cf0, l1, 64);
                half8 vA = ((const half8*)(wvh + (size_t)sA * DIM))[sub8];
                half8 vB = ((const half8*)(wvh + (size_t)sB * DIM))[sub8];
                #pragma unroll
                for (int k = 0; k < 8; ++k) ac[k] += (float)vA[k] * cA;
                #pragma unroll
                for (int k = 0; k < 8; ++k) ac[k] += (float)vB[k] * cB;
            }
            if (jj < rounds) {
                int l0 = 8 * jj + g8;
                int   sA = __shfl(s0, l0, 64);
                float cA = __shfl(cf0, l0, 64);
                half8 vA = ((const half8*)(wvh + (size_t)sA * DIM))[sub8];
                #pragma unroll
                for (int k = 0; k < 8; ++k) ac[k] += (float)vA[k] * cA;
            }
            #pragma unroll
            for (int off = 8; off < 64; off <<= 1) {
                #pragma unroll
                for (int k = 0; k < 8; ++k) ac[k] += __shfl_xor(ac[k], off, 64);
            }
            if (g8 == 0) {
                float4* orow = (float4*)(out + (size_t)vg * DIM + sub8 * 8);
                float4 o0; o0.x = ac[0]; o0.y = ac[1]; o0.z = ac[2]; o0.w = ac[3];
                float4 o1; o1.x = ac[4]; o1.y = ac[5]; o1.z = ac[6]; o1.w = ac[7];
                orow[0] = o0; orow[1] = o1;
            }
        } else {
            double denom = 0.0;
            for (int base = 0; base < deg; base += 64) {
                int mm = deg - base; if (mm > 64) mm = 64;
                double c = 0.0;
                if (lane < mm) {
                    int s = csr[st + base + lane];
                    c = h_src[s] + hd;
                }
                #pragma unroll
                for (int off = 32; off > 0; off >>= 1) c += __shfl_xor(c, off, 64);
                denom += c;
            }
            double inv = 1.0 / denom;
            float acc = 0.f;
            for (int base = 0; base < deg; base += 64) {
                int mm = deg - base; if (mm > 64) mm = 64;
                int s1 = 0; float cf1 = 0.f;
                if (lane < mm) {
                    s1 = csr[st + base + lane];
                    cf1 = (float)((h_src[s1] + hd) * inv);
                }
                for (int q = 0; q < mm; ++q) {
                    int s = lane_bci(s1, q);
                    float cf = lane_bcf(cf1, q);
                    acc += (float)wvh[(size_t)s * DIM + lane] * cf;
                }
            }
            out[(size_t)vg * DIM + lane] = acc;
        }
    }
}

// ---------------------------------------------------------------------------
// Launch — 4 dispatches: fat, scan, scatter, sortgather. No memset.
// ---------------------------------------------------------------------------
extern "C" void kernel_launch(void* const* d_in, const int* in_sizes, int n_in,
                              void* d_out, int out_size, void* d_ws, size_t ws_size,
                              hipStream_t stream) {
    const float* d_u = (const float*)d_in[0];
    const float* p_u = (const float*)d_in[1];
    const float* w_q = (const float*)d_in[2];
    const float* w_k = (const float*)d_in[3];
    const float* w_v = (const float*)d_in[4];
    const float* e1  = (const float*)d_in[5];
    const float* e2  = (const float*)d_in[6];
    const int*   src = (const int*)d_in[7];
    const int*   dst = (const int*)d_in[8];
    float* out = (float*)d_out;

    // Workspace: doubles first (8B aligned), then halfs, then ints.
    double* h_src  = (double*)d_ws;
    double* h_dst  = h_src + N_NODES;
    _Float16* wvh  = (_Float16*)(h_dst + N_NODES);      // N_NODES*DIM halfs
    int* counters  = (int*)(wvh + (size_t)N_NODES * DIM); // NCTR ints
    unsigned int* pub = (unsigned int*)(counters + NCTR); // 1024
    int* pairs     = (int*)(pub + 1024);                  // N_EDGES ints

    fat_kernel<<<NEB + NW_BLKS, 256, 0, stream>>>(
        dst, d_u, p_u, w_v, w_q, w_k, e1, e2, h_src, h_dst, wvh,
        counters, pub);

    scan_kernel<<<NSB, 1024, 0, stream>>>(counters, pub);

    scatter_kernel<<<NEB, 256, 0, stream>>>(src, dst, counters, pairs);

    sortgather_kernel<<<NBKT, 1024, 0, stream>>>(
        counters, pairs, h_src, h_dst, wvh, out);
}